// Round 7
// baseline (237.117 us; speedup 1.0000x reference)
//
#include <hip/hip_runtime.h>

// MN neuron forward sim: T=1000 sequential steps, 64x512 independent chains.
// Round 8: R7b base + structurally-guaranteed LDS read-ahead (the last
// unfalsified stall theory: ds_read sunk-to-use adds ~120 cyc to every step's
// recurrence; VGPR=32..52 across R4/R7b proves the allocator sinks reads).
//   - Consumer inner loop is ROLLED (#pragma unroll 1) with a 4-deep rotating
//     register window X0..X3: 2 steps + 2 prefetch reads per iteration. A
//     read's use is 2 iterations (~2 steps, >300 cyc) after issue, and reads
//     cannot sink across a loop backedge -- the guarantee R5's asm pins tried
//     and failed to give (pins serialized scheduling; discounted evidence).
//   - Chunk-boundary: last 2 iterations prefetch rows 0..3 of the NEXT chunk,
//     so producer keeps 2 chunks resident: NBUF=4, counted vmcnt(5).
//   - Keeps R7b's proven pieces: SGPR-pinned constants, LDS spike staging +
//     producer dwordx4 NT flush, raw s_barrier, s_setprio 1.
// CORRECTNESS: binary spike output => bit-exact f32 vs numpy ref:
//   exact reference op order, no FMA contraction, selects for spike resets.
// Producer ledger (5 loads/chunk; vmcnt counts its loads + its NT stores,
// stores only make waits conservative):
//   prologue: issue 0,1,2 (15 out); vmcnt(5) -> chunks 0,1 resident; B0.
//   iter c=0..49: if c+3<50 issue(c+3); wait vmcnt(5) for c<=46 (=> chunk c+2
//   resident: only c+3's 5 loads may remain) else vmcnt(0); if c>=1
//   flush(c-1) [ds_read_b128 sb -> NT global]; lgkmcnt(0); B(c+1).
//   After loop: flush(49).
// Consumer: B0; X0..X3 = chunk0 rows 0..3; per chunk: 8 rolled iters
//   (prefetch cur rows 2i+4,2i+5; steps 2i,2i+1 use X0,X1; rotate), then 2
//   straight-line iters prefetching nxt rows 0..3; lgkmcnt(0); B(c+1).
//   Rotation invariant: entering iter i, X0..X3 = rows 2i..2i+3. After the
//   tail, X0..X3 = next chunk rows 0..3. Last chunk's tail prefetch reads
//   stale buf[2] rows -- in-bounds, values discarded.
// Race checks: buf[(c+3)&3]=buf[(c-1)&3] overwrite issued after B(c);
//   consumer's reads of buf(c-1) (uses in chunk c-1, prefetch in c-2) retired
//   via lgkmcnt(0) before B(c). Writes to buf(c+1) complete before B(c),
//   before consumer's chunk-c prefetch into it. sb double-buffer as R7b.

#define T_STEPS 1000
#define B_DIM 64
#define N_DIM 512
#define BN (B_DIM * N_DIM)   // 32768

#define K_CHUNK 20
#define NCHUNK (T_STEPS / K_CHUNK)   // 50
#define NBUF 4

typedef const __attribute__((address_space(1))) void* gp_t;
typedef __attribute__((address_space(3))) void* lp_t;
typedef float f32x4 __attribute__((ext_vector_type(4)));

__device__ __forceinline__ void raw_barrier() {
    asm volatile("s_barrier" ::: "memory");
}

struct Consts {
    float k200, k20, kDT, kEL, kG, kTINF, kB, kR1, kR2, kTR;
};

__device__ __forceinline__ float mn_step(float xt, float lin, float av,
                                         float A1v, float A2v, const Consts& K,
                                         float& V, float& i1, float& i2,
                                         float& Thr)
{
#pragma clang fp contract(off)
    // identical IEEE op order to the verified kernel; constants in SGPRs
    i1 = i1 - (K.k200 * i1) * K.kDT;
    i2 = i2 - (K.k20  * i2) * K.kDT;
    float p  = lin * xt;
    float q  = p + i1;
    float r  = q + i2;
    float e  = V - K.kEL;
    float g  = K.kG * e;
    float s  = r - g;
    float d  = K.kDT * s;
    V = V + d;
    float e2 = V - K.kEL;
    float u  = av * e2;
    float w  = Thr - K.kTINF;
    float bw = K.kB * w;
    float s2 = u - bw;
    float d2 = K.kDT * s2;
    Thr = Thr + d2;
    float diff = V - Thr;
    bool  sb   = diff > 0.0f;
    float spk  = sb ? 1.0f : 0.0f;
    float i1r = (K.kR1 * i1) + A1v;
    float i2r = (K.kR2 * i2) + A2v;
    i1  = sb ? i1r : i1;
    i2  = sb ? i2r : i2;
    float tm = fmaxf(Thr, K.kTR);
    Thr = sb ? tm : Thr;
    V   = sb ? K.kEL : V;                   // VR == EL == -0.07f (same bits)
    return spk;
}

__global__ __launch_bounds__(128, 1) void mn_neuron_kernel(
    const float* __restrict__ x, const float* __restrict__ linear,
    const float* __restrict__ a, const float* __restrict__ A1,
    const float* __restrict__ A2, float* __restrict__ out)
{
#pragma clang fp contract(off)
    __shared__ float xb_buf[NBUF][K_CHUNK][64];   // staged x (quad buffer)
    __shared__ float sb_buf[2][K_CHUNK][64];      // staged spikes

    const int lane = threadIdx.x & 63;
    const int wid  = threadIdx.x >> 6;     // 0 = consumer, 1 = producer
    const int blk  = blockIdx.x;

    if (wid == 1) {
        // ---- producer: x staging + spike flush ----
        const float* pl = x + (size_t)(lane >> 4) * BN
                            + (size_t)blk * 64 + (size_t)(lane & 15) * 4;
        float* outp = out + (size_t)blk * 64;

        auto issue = [&](int k) {   // chunk k's 5 width-16 loads -> xb[k&3]
            const float* pc = pl + (size_t)(k * K_CHUNK) * BN;
            float* dst = &xb_buf[k & (NBUF - 1)][0][0];
#pragma unroll
            for (int s5 = 0; s5 < K_CHUNK / 4; ++s5) {
                __builtin_amdgcn_global_load_lds(
                    (gp_t)(pc + (size_t)(s5 * 4) * BN),
                    (lp_t)(dst + s5 * 4 * 64), 16, 0, 0);
            }
        };

        const int r0 = lane >> 4;          // 0..3
        const int c4 = (lane & 15) * 4;    // 0,4,..,60
        auto flush = [&](int k) {          // spikes of chunk k -> HBM
            const int kb = k & 1;
#pragma unroll
            for (int pz = 0; pz < K_CHUNK / 4; ++pz) {
                const int row = pz * 4 + r0;
                const f32x4 v = *reinterpret_cast<const f32x4*>(
                    &sb_buf[kb][row][c4]);                       // ds_read_b128
                f32x4* dp = reinterpret_cast<f32x4*>(
                    outp + (size_t)(k * K_CHUNK + row) * BN + c4);
                __builtin_nontemporal_store(v, dp);              // dwordx4 nt
            }
        };

        issue(0); issue(1); issue(2);                            // 15 out
        asm volatile("s_waitcnt vmcnt(5)" ::: "memory");         // 0,1 resident
        raw_barrier();                                           // B0

        for (int c = 0; c < NCHUNK; ++c) {
            if (c + 3 < NCHUNK) issue(c + 3);
            if (c <= NCHUNK - 4) {
                // only chunk c+3's 5 loads may remain -> c+2 resident
                asm volatile("s_waitcnt vmcnt(5)" ::: "memory");
            } else {
                asm volatile("s_waitcnt vmcnt(0)" ::: "memory");
            }
            if (c >= 1) flush(c - 1);
            asm volatile("s_waitcnt lgkmcnt(0)" ::: "memory");   // sb reusable
            raw_barrier();                                       // B(c+1)
        }
        flush(NCHUNK - 1);   // after final barrier; consumer exited
    } else {
        // ---- consumer: pure recurrence, guaranteed read-ahead ----
        const int idx = blk * 64 + lane;       // b*N + n
        const int n   = idx & (N_DIM - 1);

        const float lin = linear[n];
        const float av  = a[n];
        const float A1v = A1[n];
        const float A2v = A2[n];

        Consts K = {200.0f, 20.0f, 0.01f, -0.07f,
                    45.24007797241211f, -0.05f, 12.77495288848877f,
                    0.3858567178249359f, -1.1421641111373901f, -0.06f};
        asm volatile("" : "+s"(K.k200), "+s"(K.k20), "+s"(K.kDT),
                          "+s"(K.kEL), "+s"(K.kG), "+s"(K.kTINF),
                          "+s"(K.kB), "+s"(K.kR1), "+s"(K.kR2), "+s"(K.kTR));

        float V   = K.kEL;
        float i1  = 0.0f;
        float i2  = 0.0f;
        float Thr = K.kTINF;

        asm volatile("s_setprio 1" ::: "memory");
        raw_barrier();                                           // B0

        // window prologue: chunk 0 rows 0..3 (resident since B0)
        const float* c0 = &xb_buf[0][0][lane];
        float X0 = c0[0 * 64];
        float X1 = c0[1 * 64];
        float X2 = c0[2 * 64];
        float X3 = c0[3 * 64];

        for (int c = 0; c < NCHUNK; ++c) {
            const float* cur = &xb_buf[c & (NBUF - 1)][0][lane];
            const float* nxt = &xb_buf[(c + 1) & (NBUF - 1)][0][lane];
            float*       dst = &sb_buf[c & 1][0][lane];

            // rolled: reads cannot sink across the backedge; a read's use is
            // 2 iterations (~2 full steps) later -> LDS latency fully hidden.
#pragma unroll 1
            for (int i = 0; i < 8; ++i) {
                float p0 = cur[(2 * i + 4) * 64];
                float p1 = cur[(2 * i + 5) * 64];
                float s0 = mn_step(X0, lin, av, A1v, A2v, K, V, i1, i2, Thr);
                dst[(2 * i) * 64] = s0;
                float s1 = mn_step(X1, lin, av, A1v, A2v, K, V, i1, i2, Thr);
                dst[(2 * i + 1) * 64] = s1;
                X0 = X2; X1 = X3; X2 = p0; X3 = p1;
            }
            // tail: steps 16..19, prefetch next chunk rows 0..3 (resident:
            // producer guarantees chunk c+1 before B(c)).
            {
                float p0 = nxt[0 * 64];
                float p1 = nxt[1 * 64];
                dst[16 * 64] = mn_step(X0, lin, av, A1v, A2v, K, V, i1, i2, Thr);
                dst[17 * 64] = mn_step(X1, lin, av, A1v, A2v, K, V, i1, i2, Thr);
                X0 = X2; X1 = X3; X2 = p0; X3 = p1;
                p0 = nxt[2 * 64];
                p1 = nxt[3 * 64];
                dst[18 * 64] = mn_step(X0, lin, av, A1v, A2v, K, V, i1, i2, Thr);
                dst[19 * 64] = mn_step(X1, lin, av, A1v, A2v, K, V, i1, i2, Thr);
                X0 = X2; X1 = X3; X2 = p0; X3 = p1;
            }
            // spike writes visible to producer; all reads retired before the
            // producer may overwrite buf (c-1)
            asm volatile("s_waitcnt lgkmcnt(0)" ::: "memory");
            raw_barrier();                                       // B(c+1)
        }
    }
}

extern "C" void kernel_launch(void* const* d_in, const int* in_sizes, int n_in,
                              void* d_out, int out_size, void* d_ws, size_t ws_size,
                              hipStream_t stream) {
    const float* x      = (const float*)d_in[0];
    const float* linear = (const float*)d_in[1];
    const float* a      = (const float*)d_in[2];
    const float* A1     = (const float*)d_in[3];
    const float* A2     = (const float*)d_in[4];
    float* out = (float*)d_out;

    // 512 blocks x 128 threads (1 consumer wave + 1 producer wave each)
    mn_neuron_kernel<<<BN / 64, 128, 0, stream>>>(x, linear, a, A1, A2, out);
}